// Round 3
// baseline (122.996 us; speedup 1.0000x reference)
//
#include <hip/hip_runtime.h>
#include <hip/hip_bf16.h>
#include <math.h>

// Problem constants (fixed by reference setup_inputs)
constexpr int B = 2;
constexpr int N = 4096;   // pred points per batch
constexpr int M = 4096;   // target points per batch
constexpr int L = 512;    // latent dim

constexpr float KL_W = 0.001f;
constexpr float Q_W  = 0.1f;

// pairmin tiling
constexpr int THREADS = 256;
constexpr int QPT     = 2;               // queries per thread
constexpr int QC      = THREADS * QPT;   // 512 queries per block
constexpr int DT      = 256;             // data-tile points (4 KB LDS)
constexpr int GX      = N / QC;          // 8
constexpr int GY      = M / DT;          // 16
constexpr int GZ      = 3 * B;           // 6
constexpr int NBLOCKS = GX * GY * GZ;    // 768

// ws byte layout (16B aligned):
//   [0)        float4 packedP[B][N]   (x,y,z,|p|^2)   131072 B
//   [131072)   float4 packedT[B][M]                   131072 B
//   [262144)   uint   mins[3][B][N]                    98304 B
//   [360448)   uint   counter                              4 B
constexpr size_t OFF_P    = 0;
constexpr size_t OFF_T    = 131072;
constexpr size_t OFF_MINS = 262144;
constexpr size_t OFF_CNT  = 360448;

constexpr unsigned FLT_MAX_BITS = 0x7F7FFFFFu;

__global__ __launch_bounds__(256) void mgl_prep_kernel(
    const float* __restrict__ pred, const float* __restrict__ target,
    float4* __restrict__ packedP, float4* __restrict__ packedT,
    unsigned* __restrict__ mins, unsigned* __restrict__ counter)
{
    const int i = blockIdx.x * 256 + threadIdx.x;   // 0 .. 24575
    if (i < 3 * B * N) mins[i] = FLT_MAX_BITS;
    if (i < B * N) {
        float x = pred[i * 3 + 0], y = pred[i * 3 + 1], z = pred[i * 3 + 2];
        packedP[i] = make_float4(x, y, z, fmaf(x, x, fmaf(y, y, z * z)));
    } else if (i < 2 * B * N) {
        int j = i - B * N;
        float x = target[j * 3 + 0], y = target[j * 3 + 1], z = target[j * 3 + 2];
        packedT[j] = make_float4(x, y, z, fmaf(x, x, fmaf(y, y, z * z)));
    }
    if (i == 0) *counter = 0u;
}

__global__ __launch_bounds__(THREADS) void mgl_pairmin_kernel(
    const float4* __restrict__ packedP, const float4* __restrict__ packedT,
    const float* __restrict__ mu, const float* __restrict__ logvar,
    unsigned* __restrict__ mins, unsigned* __restrict__ counter,
    float* __restrict__ out)
{
    __shared__ float4 tile[DT];

    const int z   = blockIdx.z;     // 0..5
    const int dir = z >> 1;
    const int b   = z & 1;

    const float4* qb; const float4* db; unsigned* ob;
    if (dir == 0)      { qb = packedP + b * N; db = packedT + b * M; ob = mins + (0 * B + b) * N; }
    else if (dir == 1) { qb = packedT + b * M; db = packedP + b * N; ob = mins + (1 * B + b) * N; }
    else               { qb = packedP + b * N; db = packedP + b * N; ob = mins + (2 * B + b) * N; }

    const int q0 = blockIdx.x * QC;
    const int d0 = blockIdx.y * DT;

    // stage data tile (DT float4 = 4 KB), one 16B coalesced load per thread
    tile[threadIdx.x] = db[d0 + threadIdx.x];

    const int qi0 = q0 + threadIdx.x;
    const int qi1 = qi0 + THREADS;

    const float4 qv0 = qb[qi0];
    const float4 qv1 = qb[qi1];
    const float ax0 = -2.0f * qv0.x, ay0 = -2.0f * qv0.y, az0 = -2.0f * qv0.z;
    const float ax1 = -2.0f * qv1.x, ay1 = -2.0f * qv1.y, az1 = -2.0f * qv1.z;

    __syncthreads();

    float m0 = 3.402823466e+38f;
    float m1 = 3.402823466e+38f;

    if (dir != 2) {
        #pragma unroll 8
        for (int j = 0; j < DT; ++j) {
            float4 t = tile[j];   // same-address broadcast: conflict-free
            float v0 = fmaf(ax0, t.x, fmaf(ay0, t.y, fmaf(az0, t.z, t.w)));
            float v1 = fmaf(ax1, t.x, fmaf(ay1, t.y, fmaf(az1, t.z, t.w)));
            m0 = fminf(m0, v0);
            m1 = fminf(m1, v1);
        }
    } else {
        #pragma unroll 8
        for (int j = 0; j < DT; ++j) {
            float4 t = tile[j];
            const int dj = d0 + j;
            float v0 = fmaf(ax0, t.x, fmaf(ay0, t.y, fmaf(az0, t.z, t.w)));
            float v1 = fmaf(ax1, t.x, fmaf(ay1, t.y, fmaf(az1, t.z, t.w)));
            v0 = (dj == qi0) ? 3.402823466e+38f : v0;   // exclude diagonal (ref: +1e6 mask)
            v1 = (dj == qi1) ? 3.402823466e+38f : v1;
            m0 = fminf(m0, v0);
            m1 = fminf(m1, v1);
        }
    }

    // add |q|^2 (constant per query, commutes with min); clamp tiny negative from cancellation
    m0 = fmaxf(m0 + qv0.w, 0.0f);
    m1 = fmaxf(m1 + qv1.w, 0.0f);

    // distances >= 0 -> float bits monotonic under unsigned compare
    atomicMin(ob + qi0, __float_as_uint(m0));
    atomicMin(ob + qi1, __float_as_uint(m1));

    // ---- last-block-done finalize ----
    __threadfence();
    __shared__ int is_last;
    if (threadIdx.x == 0)
        is_last = (atomicAdd(counter, 1u) == (unsigned)(NBLOCKS - 1)) ? 1 : 0;
    __syncthreads();
    if (!is_last) return;
    __threadfence();

    const int tid = threadIdx.x;

    double sPT[B], sTP[B], sPP[B], ssPP[B];
    #pragma unroll
    for (int bb = 0; bb < B; ++bb) { sPT[bb] = 0.0; sTP[bb] = 0.0; sPP[bb] = 0.0; ssPP[bb] = 0.0; }
    double skl = 0.0;

    #pragma unroll
    for (int bb = 0; bb < B; ++bb) {
        for (int i = tid; i < N; i += THREADS) {
            unsigned upt = __hip_atomic_load(&mins[(0 * B + bb) * N + i], __ATOMIC_RELAXED, __HIP_MEMORY_SCOPE_AGENT);
            unsigned utp = __hip_atomic_load(&mins[(1 * B + bb) * N + i], __ATOMIC_RELAXED, __HIP_MEMORY_SCOPE_AGENT);
            unsigned upp = __hip_atomic_load(&mins[(2 * B + bb) * N + i], __ATOMIC_RELAXED, __HIP_MEMORY_SCOPE_AGENT);
            double vpt = (double)__uint_as_float(upt);
            double vtp = (double)__uint_as_float(utp);
            double vpp = (double)__uint_as_float(upp);
            sPT[bb]  += vpt;
            sTP[bb]  += vtp;
            sPP[bb]  += vpp;
            ssPP[bb] += vpp * vpp;
        }
    }
    for (int i = tid; i < B * L; i += THREADS) {
        double m  = (double)mu[i];
        double lv = (double)logvar[i];
        skl += 1.0 + lv - m * m - exp(lv);
    }

    __shared__ double red[9][THREADS];
    red[0][tid] = sPT[0]; red[1][tid] = sPT[1];
    red[2][tid] = sTP[0]; red[3][tid] = sTP[1];
    red[4][tid] = sPP[0]; red[5][tid] = sPP[1];
    red[6][tid] = ssPP[0]; red[7][tid] = ssPP[1];
    red[8][tid] = skl;
    __syncthreads();
    for (int s = THREADS / 2; s > 0; s >>= 1) {
        if (tid < s) {
            #pragma unroll
            for (int k = 0; k < 9; ++k) red[k][tid] += red[k][tid + s];
        }
        __syncthreads();
    }

    if (tid == 0) {
        double cd = 0.0;
        #pragma unroll
        for (int bb = 0; bb < B; ++bb)
            cd += red[0 + bb][0] / (double)N + red[2 + bb][0] / (double)M;
        cd /= (double)B;

        double density = 0.0;
        #pragma unroll
        for (int bb = 0; bb < B; ++bb) {
            double s  = red[4 + bb][0];
            double ss = red[6 + bb][0];
            double var = (ss - s * s / (double)N) / (double)(N - 1);
            density += sqrt(var > 0.0 ? var : 0.0);
        }
        density /= (double)B;

        double kl = -0.5 * red[8][0] / (double)(B * L);

        double total = cd + (double)KL_W * kl + (double)Q_W * density;
        out[0] = (float)total;
        out[1] = (float)cd;
        out[2] = (float)kl;
        out[3] = (float)density;
    }
}

extern "C" void kernel_launch(void* const* d_in, const int* in_sizes, int n_in,
                              void* d_out, int out_size, void* d_ws, size_t ws_size,
                              hipStream_t stream) {
    const float* pred   = (const float*)d_in[0];
    const float* target = (const float*)d_in[1];
    const float* mu     = (const float*)d_in[2];
    const float* logvar = (const float*)d_in[3];
    float* out = (float*)d_out;

    char* ws = (char*)d_ws;
    float4*   packedP = (float4*)(ws + OFF_P);
    float4*   packedT = (float4*)(ws + OFF_T);
    unsigned* mins    = (unsigned*)(ws + OFF_MINS);
    unsigned* counter = (unsigned*)(ws + OFF_CNT);

    mgl_prep_kernel<<<dim3((3 * B * N + 255) / 256), 256, 0, stream>>>(
        pred, target, packedP, packedT, mins, counter);
    mgl_pairmin_kernel<<<dim3(GX, GY, GZ), THREADS, 0, stream>>>(
        packedP, packedT, mu, logvar, mins, counter, out);
}

// Round 4
// 81.655 us; speedup vs baseline: 1.5063x; 1.5063x over previous
//
#include <hip/hip_runtime.h>
#include <hip/hip_bf16.h>
#include <math.h>

// Problem constants (fixed by reference setup_inputs)
constexpr int B = 2;
constexpr int N = 4096;   // pred points per batch
constexpr int M = 4096;   // target points per batch
constexpr int L = 512;    // latent dim

constexpr float KL_W = 0.001f;
constexpr float Q_W  = 0.1f;

// pairmin tiling
constexpr int THREADS = 256;
constexpr int QPT     = 2;               // queries per thread
constexpr int QC      = THREADS * QPT;   // 512 queries per block
constexpr int DT      = 256;             // data-tile points (4 KB LDS)
constexpr int GX      = N / QC;          // 8
constexpr int GY      = M / DT;          // 16
constexpr int GZ      = 3 * B;           // 6  -> 768 blocks, 12 waves/CU

// ws layout: uint mins[3][B][N]  (dir 0 = pred->target, 1 = target->pred, 2 = pred->pred)
constexpr size_t MINS_BYTES = (size_t)3 * B * N * 4;   // 96 KB

__global__ __launch_bounds__(THREADS) void mgl_pairmin_kernel(
    const float* __restrict__ pred, const float* __restrict__ target,
    unsigned* __restrict__ mins)
{
    __shared__ float4 tile[DT];

    const int z   = blockIdx.z;     // 0..5
    const int dir = z >> 1;
    const int b   = z & 1;

    const float* qb; const float* db; unsigned* ob;
    if (dir == 0)      { qb = pred   + b * N * 3; db = target + b * M * 3; ob = mins + (0 * B + b) * N; }
    else if (dir == 1) { qb = target + b * M * 3; db = pred   + b * N * 3; ob = mins + (1 * B + b) * N; }
    else               { qb = pred   + b * N * 3; db = pred   + b * N * 3; ob = mins + (2 * B + b) * N; }

    const int q0 = blockIdx.x * QC;
    const int d0 = blockIdx.y * DT;

    // stage data tile: compute |t|^2 during staging (once per point, reused by 512 queries)
    {
        const float* p = db + (size_t)(d0 + threadIdx.x) * 3;
        float x = p[0], y = p[1], zz = p[2];
        tile[threadIdx.x] = make_float4(x, y, zz, fmaf(x, x, fmaf(y, y, zz * zz)));
    }

    const int qi0 = q0 + threadIdx.x;
    const int qi1 = qi0 + THREADS;

    const float qx0 = qb[qi0 * 3 + 0], qy0 = qb[qi0 * 3 + 1], qz0 = qb[qi0 * 3 + 2];
    const float qx1 = qb[qi1 * 3 + 0], qy1 = qb[qi1 * 3 + 1], qz1 = qb[qi1 * 3 + 2];
    const float qw0 = fmaf(qx0, qx0, fmaf(qy0, qy0, qz0 * qz0));
    const float qw1 = fmaf(qx1, qx1, fmaf(qy1, qy1, qz1 * qz1));
    const float ax0 = -2.0f * qx0, ay0 = -2.0f * qy0, az0 = -2.0f * qz0;
    const float ax1 = -2.0f * qx1, ay1 = -2.0f * qy1, az1 = -2.0f * qz1;

    __syncthreads();

    float m0 = 3.402823466e+38f;
    float m1 = 3.402823466e+38f;

    if (dir != 2) {
        #pragma unroll 8
        for (int j = 0; j < DT; ++j) {
            float4 t = tile[j];   // wave-uniform address: LDS broadcast, conflict-free
            float v0 = fmaf(ax0, t.x, fmaf(ay0, t.y, fmaf(az0, t.z, t.w)));
            float v1 = fmaf(ax1, t.x, fmaf(ay1, t.y, fmaf(az1, t.z, t.w)));
            m0 = fminf(m0, v0);
            m1 = fminf(m1, v1);
        }
    } else {
        #pragma unroll 8
        for (int j = 0; j < DT; ++j) {
            float4 t = tile[j];
            const int dj = d0 + j;
            float v0 = fmaf(ax0, t.x, fmaf(ay0, t.y, fmaf(az0, t.z, t.w)));
            float v1 = fmaf(ax1, t.x, fmaf(ay1, t.y, fmaf(az1, t.z, t.w)));
            v0 = (dj == qi0) ? 3.402823466e+38f : v0;   // exclude diagonal (ref masks with +1e6)
            v1 = (dj == qi1) ? 3.402823466e+38f : v1;
            m0 = fminf(m0, v0);
            m1 = fminf(m1, v1);
        }
    }

    // add |q|^2 (constant per query, commutes with min); clamp tiny negative from cancellation
    m0 = fmaxf(m0 + qw0, 0.0f);
    m1 = fmaxf(m1 + qw1, 0.0f);

    // distances >= 0 -> float bits monotonic under unsigned compare
    atomicMin(ob + qi0, __float_as_uint(m0));
    atomicMin(ob + qi1, __float_as_uint(m1));
}

__global__ __launch_bounds__(256) void mgl_finalize_kernel(
    const unsigned* __restrict__ mins, const float* __restrict__ mu,
    const float* __restrict__ logvar, float* __restrict__ out)
{
    const int tid = threadIdx.x;   // 256 threads; plain loads (kernel boundary = coherence)

    double sPT[B], sTP[B], sPP[B], ssPP[B];
    #pragma unroll
    for (int bb = 0; bb < B; ++bb) { sPT[bb] = 0.0; sTP[bb] = 0.0; sPP[bb] = 0.0; ssPP[bb] = 0.0; }
    double skl = 0.0;

    #pragma unroll
    for (int bb = 0; bb < B; ++bb) {
        for (int i = tid; i < N; i += 256) {
            double vpt = (double)__uint_as_float(mins[(0 * B + bb) * N + i]);
            double vtp = (double)__uint_as_float(mins[(1 * B + bb) * N + i]);
            double vpp = (double)__uint_as_float(mins[(2 * B + bb) * N + i]);
            sPT[bb]  += vpt;
            sTP[bb]  += vtp;
            sPP[bb]  += vpp;
            ssPP[bb] += vpp * vpp;
        }
    }
    for (int i = tid; i < B * L; i += 256) {
        double m  = (double)mu[i];
        double lv = (double)logvar[i];
        skl += 1.0 + lv - m * m - exp(lv);
    }

    __shared__ double red[9][256];
    red[0][tid] = sPT[0]; red[1][tid] = sPT[1];
    red[2][tid] = sTP[0]; red[3][tid] = sTP[1];
    red[4][tid] = sPP[0]; red[5][tid] = sPP[1];
    red[6][tid] = ssPP[0]; red[7][tid] = ssPP[1];
    red[8][tid] = skl;
    __syncthreads();
    for (int s = 128; s > 0; s >>= 1) {
        if (tid < s) {
            #pragma unroll
            for (int k = 0; k < 9; ++k) red[k][tid] += red[k][tid + s];
        }
        __syncthreads();
    }

    if (tid == 0) {
        double cd = 0.0;
        #pragma unroll
        for (int bb = 0; bb < B; ++bb)
            cd += red[0 + bb][0] / (double)N + red[2 + bb][0] / (double)M;
        cd /= (double)B;

        double density = 0.0;
        #pragma unroll
        for (int bb = 0; bb < B; ++bb) {
            double s  = red[4 + bb][0];
            double ss = red[6 + bb][0];
            double var = (ss - s * s / (double)N) / (double)(N - 1);
            density += sqrt(var > 0.0 ? var : 0.0);
        }
        density /= (double)B;

        double kl = -0.5 * red[8][0] / (double)(B * L);

        double total = cd + (double)KL_W * kl + (double)Q_W * density;
        out[0] = (float)total;
        out[1] = (float)cd;
        out[2] = (float)kl;
        out[3] = (float)density;
    }
}

extern "C" void kernel_launch(void* const* d_in, const int* in_sizes, int n_in,
                              void* d_out, int out_size, void* d_ws, size_t ws_size,
                              hipStream_t stream) {
    const float* pred   = (const float*)d_in[0];
    const float* target = (const float*)d_in[1];
    const float* mu     = (const float*)d_in[2];
    const float* logvar = (const float*)d_in[3];
    float* out = (float*)d_out;

    unsigned* mins = (unsigned*)d_ws;

    // 0x7F7F7F7F == 3.3961514e38f: valid "infinity" init for squared distances
    hipMemsetAsync(mins, 0x7F, MINS_BYTES, stream);
    mgl_pairmin_kernel<<<dim3(GX, GY, GZ), THREADS, 0, stream>>>(pred, target, mins);
    mgl_finalize_kernel<<<1, 256, 0, stream>>>(mins, mu, logvar, out);
}